// Round 5
// baseline (317.885 us; speedup 1.0000x reference)
//
#include <hip/hip_runtime.h>
#include <hip/hip_fp16.h>

// ---------------------------------------------------------------------------
// GCN 2-layer forward:  out = log_softmax( A_hat * relu(A_hat * (x W1) + b1) W2 + b2 )
// A_hat = D^-1/2 (A + I) D^-1/2, deg on dst. Edge index arrives as int32.
//
// R12: pull gather MLP doubled. pull_agg1: 16 full rows (256B each) in flight
// per wave per iteration (4KB); pull_agg2: 32 edges/iter (16 loads per
// lane-half). fp16 tree depth kept at 4 (same rounding as r11). Wave-uniform
// edge range -> scalar col loads. CSR build + MFMA GEMMs unchanged.
// ---------------------------------------------------------------------------

#define BSHIFT 9
#define BSIZE  512            // nodes per bucket; NB = ceil(N/512) = 196 < 256
#define P2_T   1024
#define P2_I   16             // edges staged per thread in partition pass

using half8  = __attribute__((ext_vector_type(8))) _Float16;
using half2v = __attribute__((ext_vector_type(2))) _Float16;
using f32x4  = __attribute__((ext_vector_type(4))) float;

// --- pass 1: per-bucket edge counts (coalesced dst read, LDS histogram) ----
__global__ __launch_bounds__(256) void bucket_hist_kernel(const int* __restrict__ dst, int E,
                                                          unsigned int* __restrict__ bcount, int NB) {
    __shared__ unsigned int h[256];
    int t = threadIdx.x;
    h[t] = 0u;
    __syncthreads();
    for (int i = blockIdx.x * 256 + t; i < E; i += gridDim.x * 256)
        atomicAdd(&h[dst[i] >> BSHIFT], 1u);
    __syncthreads();
    if (t < NB && h[t]) atomicAdd(&bcount[t], h[t]);
}

// --- scan bucket counts -> bucket_base bb[0..NB], bucket_fill bf -----------
__global__ __launch_bounds__(256) void bucket_scan_kernel(const unsigned int* __restrict__ bcount,
                                                          unsigned int* __restrict__ bb,
                                                          unsigned int* __restrict__ bf,
                                                          int NB, int E) {
    __shared__ unsigned int s[256];
    int t = threadIdx.x;
    unsigned int v = (t < NB) ? bcount[t] : 0u;
    s[t] = v;
    __syncthreads();
    for (int off = 1; off < 256; off <<= 1) {
        unsigned int u = s[t];
        if (t >= off) u += s[t - off];
        __syncthreads();
        s[t] = u;
        __syncthreads();
    }
    if (t < NB) {
        unsigned int ex = s[t] - v;
        bb[t] = ex;
        bf[t] = ex;
    }
    if (t == 0) bb[NB] = (unsigned int)E;
}

// --- pass 2: partition edges into dst-buckets, packed src|dstLocal<<17 -----
__global__ __launch_bounds__(1024) void partition_kernel(const int* __restrict__ src,
                                                         const int* __restrict__ dst,
                                                         unsigned int* __restrict__ bucket_fill,
                                                         unsigned int* __restrict__ ebuf,
                                                         int E, int NB) {
    __shared__ unsigned int hist[256];
    __shared__ unsigned int cur[256];
    int t = threadIdx.x;
    if (t < 256) hist[t] = 0u;
    __syncthreads();
    size_t base = (size_t)blockIdx.x * (P2_T * P2_I);
    int sv[P2_I], dv[P2_I];
#pragma unroll
    for (int i = 0; i < P2_I; ++i) {
        size_t idx = base + (size_t)i * P2_T + t;
        if (idx < (size_t)E) {
            sv[i] = src[idx];
            dv[i] = dst[idx];
            atomicAdd(&hist[dv[i] >> BSHIFT], 1u);
        } else dv[i] = -1;
    }
    __syncthreads();
    if (t < NB && hist[t] > 0u) cur[t] = atomicAdd(&bucket_fill[t], hist[t]);
    __syncthreads();
#pragma unroll
    for (int i = 0; i < P2_I; ++i) {
        if (dv[i] >= 0) {
            int b = dv[i] >> BSHIFT;
            unsigned int pos = atomicAdd(&cur[b], 1u);
            ebuf[pos] = (unsigned int)sv[i] | ((unsigned int)(dv[i] & (BSIZE - 1)) << 17);
        }
    }
}

// --- pass 3: per-bucket deg/dinv/rowptr in LDS + scatter; cursor=rowend ----
__global__ __launch_bounds__(256) void bucket_scatter2_kernel(const unsigned int* __restrict__ ebuf,
                                                              const unsigned int* __restrict__ bb,
                                                              unsigned int* __restrict__ cursor,
                                                              unsigned int* __restrict__ deg,
                                                              float* __restrict__ dinv,
                                                              int* __restrict__ col, int N) {
    __shared__ unsigned int ldeg[BSIZE];
    __shared__ unsigned int lcur[BSIZE];
    __shared__ unsigned int part[256];
    int b = blockIdx.x, t = threadIdx.x;
    int node0 = b << BSHIFT;
    int nn = min(BSIZE, N - node0);
    ldeg[t] = 0u;
    ldeg[t + 256] = 0u;
    __syncthreads();
    unsigned int e0 = bb[b], e1 = bb[b + 1];
    for (unsigned int e = e0 + t; e < e1; e += 256)
        atomicAdd(&ldeg[ebuf[e] >> 17], 1u);
    __syncthreads();
    unsigned int a0 = ldeg[2 * t], a1 = ldeg[2 * t + 1];
    part[t] = a0 + a1;
    __syncthreads();
    for (int off = 1; off < 256; off <<= 1) {
        unsigned int u = part[t];
        if (t >= off) u += part[t - off];
        __syncthreads();
        part[t] = u;
        __syncthreads();
    }
    unsigned int ex = part[t] - (a0 + a1);
    lcur[2 * t]     = e0 + ex;
    lcur[2 * t + 1] = e0 + ex + a0;
    __syncthreads();
    for (unsigned int e = e0 + t; e < e1; e += 256) {
        unsigned int p = ebuf[e];
        unsigned int pos = atomicAdd(&lcur[p >> 17], 1u);
        col[pos] = (int)(p & 0x1FFFFu);
    }
    __syncthreads();
    for (int i = t; i < nn; i += 256) {
        unsigned int d = ldeg[i];
        deg[node0 + i] = d;
        dinv[node0 + i] = rsqrtf((float)(d + 1u));
        cursor[node0 + i] = lcur[i];
    }
}

// --- swizzle W1 (128x128) and W2 (128x64) into MFMA B-fragment order -------
// w1s[((c*4+s)*64+l)*8+j] = W[k][n], k=(l>>4)*8+j+32s, n=16c+(l&15)
__global__ __launch_bounds__(256) void swizzle_w_kernel(const float* __restrict__ W1,
                                                        const float* __restrict__ W2,
                                                        __half* __restrict__ w1s,
                                                        __half* __restrict__ w2s) {
    int t = threadIdx.x;
    for (int i = t; i < 8 * 4 * 64 * 8; i += 256) {   // W1: 8 col-tiles
        int j = i & 7, l = (i >> 3) & 63, s = (i >> 9) & 3, c = i >> 11;
        int k = ((l >> 4) * 8) + j + 32 * s;
        int nn = 16 * c + (l & 15);
        w1s[i] = __float2half(W1[k * 128 + nn]);
    }
    for (int i = t; i < 4 * 4 * 64 * 8; i += 256) {   // W2: 4 col-tiles
        int j = i & 7, l = (i >> 3) & 63, s = (i >> 9) & 3, c = i >> 11;
        int k = ((l >> 4) * 8) + j + 32 * s;
        int nn = 16 * c + (l & 15);
        w2s[i] = __float2half(W2[k * 64 + nn]);
    }
}

// --- GEMM1 (MFMA): Y[r,128] = f16( dinv[r] * (X[r,128] @ W1) ), X fp32 -----
__global__ __launch_bounds__(256) void gemm1_mfma_kernel(const float* __restrict__ X,
                                                         const __half* __restrict__ w1s,
                                                         const float* __restrict__ dinv,
                                                         __half* __restrict__ Y, int n) {
    int t = threadIdx.x;
    int wave = t >> 6, lane = t & 63;
    int quad = lane >> 4, m = lane & 15;
    int rowbase = blockIdx.x * 64 + wave * 16;
    int arow = rowbase + m;
    bool aok = arow < n;
    const float* xr = X + (size_t)arow * 128 + quad * 8;

    half8 afrag[4];
#pragma unroll
    for (int s = 0; s < 4; ++s) {
        float4 p0 = make_float4(0.f, 0.f, 0.f, 0.f), p1 = p0;
        if (aok) {
            p0 = *(const float4*)(xr + s * 32);
            p1 = *(const float4*)(xr + s * 32 + 4);
        }
        afrag[s][0] = (_Float16)p0.x; afrag[s][1] = (_Float16)p0.y;
        afrag[s][2] = (_Float16)p0.z; afrag[s][3] = (_Float16)p0.w;
        afrag[s][4] = (_Float16)p1.x; afrag[s][5] = (_Float16)p1.y;
        afrag[s][6] = (_Float16)p1.z; afrag[s][7] = (_Float16)p1.w;
    }

    const half8* bp = (const half8*)w1s;
    f32x4 acc[8];
#pragma unroll
    for (int c = 0; c < 8; ++c) acc[c] = (f32x4){0.f, 0.f, 0.f, 0.f};
#pragma unroll
    for (int c = 0; c < 8; ++c)
#pragma unroll
        for (int s = 0; s < 4; ++s)
            acc[c] = __builtin_amdgcn_mfma_f32_16x16x32_f16(afrag[s], bp[(c * 4 + s) * 64 + lane], acc[c], 0, 0, 0);

#pragma unroll
    for (int i = 0; i < 4; ++i) {
        int row = rowbase + quad * 4 + i;
        if (row < n) {
            float w = dinv[row];
            __half* yr = Y + (size_t)row * 128 + m;
#pragma unroll
            for (int c = 0; c < 8; ++c) yr[c * 16] = __float2half(acc[c][i] * w);
        }
    }
}

// --- GEMM2 (MFMA): Y[r,64] = f16( dinv[r] * (Xh[r,128] @ W2) ), X fp16 -----
__global__ __launch_bounds__(256) void gemm2_mfma_kernel(const __half* __restrict__ X,
                                                         const __half* __restrict__ w2s,
                                                         const float* __restrict__ dinv,
                                                         __half* __restrict__ Y, int n) {
    int t = threadIdx.x;
    int wave = t >> 6, lane = t & 63;
    int quad = lane >> 4, m = lane & 15;
    int rowbase = blockIdx.x * 64 + wave * 16;
    int arow = rowbase + m;
    bool aok = arow < n;
    const __half* xr = X + (size_t)arow * 128 + quad * 8;

    half8 afrag[4];
#pragma unroll
    for (int s = 0; s < 4; ++s) {
        if (aok) afrag[s] = *(const half8*)(xr + s * 32);
        else     afrag[s] = (half8){0, 0, 0, 0, 0, 0, 0, 0};
    }

    const half8* bp = (const half8*)w2s;
    f32x4 acc[4];
#pragma unroll
    for (int c = 0; c < 4; ++c) acc[c] = (f32x4){0.f, 0.f, 0.f, 0.f};
#pragma unroll
    for (int c = 0; c < 4; ++c)
#pragma unroll
        for (int s = 0; s < 4; ++s)
            acc[c] = __builtin_amdgcn_mfma_f32_16x16x32_f16(afrag[s], bp[(c * 4 + s) * 64 + lane], acc[c], 0, 0, 0);

#pragma unroll
    for (int i = 0; i < 4; ++i) {
        int row = rowbase + quad * 4 + i;
        if (row < n) {
            float w = dinv[row];
            __half* yr = Y + (size_t)row * 64 + m;
#pragma unroll
            for (int c = 0; c < 4; ++c) yr[c * 16] = __float2half(acc[c][i] * w);
        }
    }
}

// --- pull layer 1: H[d] = relu(dinv[d]*(T'[d] + sum T'[col]) + b1), F=128 --
// R12: 1 node/wave; one full 256B row per wave load; 16 rows in flight.
__global__ __launch_bounds__(256) void pull_agg1_kernel(const __half* __restrict__ T,
                                                        const int* __restrict__ col,
                                                        const unsigned int* __restrict__ cursor,
                                                        const unsigned int* __restrict__ deg,
                                                        const float* __restrict__ dinv,
                                                        const float* __restrict__ b1,
                                                        __half* __restrict__ H, int N) {
    int node = blockIdx.x * 4 + (threadIdx.x >> 6);
    if (node >= N) return;
    int lane = threadIdx.x & 63;
    unsigned int end = cursor[node];
    unsigned int e = end - deg[node];
    end = __builtin_amdgcn_readfirstlane(end);
    e   = __builtin_amdgcn_readfirstlane(e);
    const half2v* __restrict__ Tv = (const half2v*)T;   // row = 64 half2

    half2v self = Tv[(unsigned int)node * 64u + lane];
    float acc0 = (float)self[0], acc1 = (float)self[1];

    for (; e + 16 <= end; e += 16) {                    // 16 rows in flight
        unsigned int s[16];
#pragma unroll
        for (int k = 0; k < 16; ++k) s[k] = (unsigned int)col[e + k];
        half2v v[16];
#pragma unroll
        for (int k = 0; k < 16; ++k) v[k] = Tv[s[k] * 64u + lane];
        half2v t0 = (v[0] + v[1]) + (v[2] + v[3]);      // fp16 trees of 4
        half2v t1 = (v[4] + v[5]) + (v[6] + v[7]);
        half2v t2 = (v[8] + v[9]) + (v[10] + v[11]);
        half2v t3 = (v[12] + v[13]) + (v[14] + v[15]);
        acc0 += ((float)t0[0] + (float)t1[0]) + ((float)t2[0] + (float)t3[0]);
        acc1 += ((float)t0[1] + (float)t1[1]) + ((float)t2[1] + (float)t3[1]);
    }
    for (; e + 4 <= end; e += 4) {
        unsigned int s0 = (unsigned int)col[e];
        unsigned int s1 = (unsigned int)col[e + 1];
        unsigned int s2 = (unsigned int)col[e + 2];
        unsigned int s3 = (unsigned int)col[e + 3];
        half2v v0 = Tv[s0 * 64u + lane];
        half2v v1 = Tv[s1 * 64u + lane];
        half2v v2 = Tv[s2 * 64u + lane];
        half2v v3 = Tv[s3 * 64u + lane];
        half2v t = (v0 + v1) + (v2 + v3);
        acc0 += (float)t[0];
        acc1 += (float)t[1];
    }
    for (; e < end; ++e) {                              // <=3 singles, fp32 path
        half2v v0 = Tv[(unsigned int)col[e] * 64u + lane];
        acc0 += (float)v0[0];
        acc1 += (float)v0[1];
    }

    float w = dinv[node];
    float2 b = ((const float2*)b1)[lane];
    float hx = fmaxf(fmaf(w, acc0, b.x), 0.f);
    float hy = fmaxf(fmaf(w, acc1, b.y), 0.f);
    ((__half2*)H)[(unsigned int)node * 64u + lane] = __floats2half2_rn(hx, hy);
}

// --- pull layer 2 + logsoftmax: out[d] = lsm(dinv[d]*sum + b2), F=64 -------
// R12: 1 node/wave; 2 rows per wave load (lane-half split); 32 edges/iter
// (16 loads per half in flight); one shfl_xor(32) combine, LSM over 32 lanes.
__global__ __launch_bounds__(256) void pull_agg2_kernel(const __half* __restrict__ T,
                                                        const int* __restrict__ col,
                                                        const unsigned int* __restrict__ cursor,
                                                        const unsigned int* __restrict__ deg,
                                                        const float* __restrict__ dinv,
                                                        const float* __restrict__ b2,
                                                        float* __restrict__ OUT, int N) {
    int node = blockIdx.x * 4 + (threadIdx.x >> 6);
    if (node >= N) return;
    int lane = threadIdx.x & 63;
    int h = lane >> 5, c2 = lane & 31;                  // edge-half / col pair
    unsigned int end = cursor[node];
    unsigned int e = end - deg[node];
    end = __builtin_amdgcn_readfirstlane(end);
    e   = __builtin_amdgcn_readfirstlane(e);
    const half2v* __restrict__ Tv = (const half2v*)T;   // row = 32 half2

    float acc0 = 0.f, acc1 = 0.f;
    if (h == 0) {                                       // self loop on half 0
        half2v s = Tv[(unsigned int)node * 32u + c2];
        acc0 = (float)s[0];
        acc1 = (float)s[1];
    }

    for (; e + 32 <= end; e += 32) {                    // 16 rows/half in flight
        unsigned int s[16];
#pragma unroll
        for (int k = 0; k < 16; ++k) s[k] = (unsigned int)col[e + 2 * k + h];
        half2v v[16];
#pragma unroll
        for (int k = 0; k < 16; ++k) v[k] = Tv[s[k] * 32u + c2];
        half2v t0 = (v[0] + v[1]) + (v[2] + v[3]);
        half2v t1 = (v[4] + v[5]) + (v[6] + v[7]);
        half2v t2 = (v[8] + v[9]) + (v[10] + v[11]);
        half2v t3 = (v[12] + v[13]) + (v[14] + v[15]);
        acc0 += ((float)t0[0] + (float)t1[0]) + ((float)t2[0] + (float)t3[0]);
        acc1 += ((float)t0[1] + (float)t1[1]) + ((float)t2[1] + (float)t3[1]);
    }
    for (; e + 8 <= end; e += 8) {                      // 4 rows/half
        unsigned int s0 = (unsigned int)col[e + h];
        unsigned int s1 = (unsigned int)col[e + 2 + h];
        unsigned int s2 = (unsigned int)col[e + 4 + h];
        unsigned int s3 = (unsigned int)col[e + 6 + h];
        half2v v0 = Tv[s0 * 32u + c2];
        half2v v1 = Tv[s1 * 32u + c2];
        half2v v2 = Tv[s2 * 32u + c2];
        half2v v3 = Tv[s3 * 32u + c2];
        half2v t = (v0 + v1) + (v2 + v3);
        acc0 += (float)t[0];
        acc1 += (float)t[1];
    }
    for (; e + 2 <= end; e += 2) {                      // 1 row/half
        half2v v0 = Tv[(unsigned int)col[e + h] * 32u + c2];
        acc0 += (float)v0[0];
        acc1 += (float)v0[1];
    }
    if (e < end && h == 0) {                            // final odd edge
        half2v v0 = Tv[(unsigned int)col[e] * 32u + c2];
        acc0 += (float)v0[0];
        acc1 += (float)v0[1];
    }

    acc0 += __shfl_xor(acc0, 32);                       // combine halves
    acc1 += __shfl_xor(acc1, 32);

    float w = dinv[node];
    float2 b = ((const float2*)b2)[c2];
    float vx = fmaf(w, acc0, b.x);
    float vy = fmaf(w, acc1, b.y);
    float m = fmaxf(vx, vy);
#pragma unroll
    for (int off = 16; off > 0; off >>= 1) m = fmaxf(m, __shfl_xor(m, off));
    float sum = __expf(vx - m) + __expf(vy - m);
#pragma unroll
    for (int off = 16; off > 0; off >>= 1) sum += __shfl_xor(sum, off);
    float ls = m + logf(sum);
    if (h == 0) {
        float2 o;
        o.x = vx - ls;
        o.y = vy - ls;
        ((float2*)OUT)[(unsigned int)node * 32u + c2] = o;
    }
}

extern "C" void kernel_launch(void* const* d_in, const int* in_sizes, int n_in,
                              void* d_out, int out_size, void* d_ws, size_t ws_size,
                              hipStream_t stream) {
    const float* x   = (const float*)d_in[0];
    const int*   ei  = (const int*)d_in[1];   // int32 per harness contract
    const float* W1  = (const float*)d_in[2];
    const float* b1  = (const float*)d_in[3];
    const float* W2  = (const float*)d_in[4];
    const float* b2  = (const float*)d_in[5];
    float*       out = (float*)d_out;

    const int N = in_sizes[0] / 128;      // 100000
    const int E = in_sizes[1] / 2;        // 1600000
    const int* src = ei;
    const int* dst = ei + E;
    const int NB = (N + BSIZE - 1) >> BSHIFT;   // dst buckets (196 <= 256)

    // workspace layout
    char* ws = (char*)d_ws;
    size_t off = 0;
    auto alloc = [&](size_t bytes) { void* p = ws + off; off = (off + bytes + 255) & ~(size_t)255; return p; };
    unsigned int* deg    = (unsigned int*)alloc((size_t)N * 4);
    float*        dinv   = (float*)alloc((size_t)N * 4);
    unsigned int* cursor = (unsigned int*)alloc((size_t)N * 4);
    unsigned int* bcount = (unsigned int*)alloc(256 * 4);
    unsigned int* bb     = (unsigned int*)alloc(257 * 4);       // bucket_base
    unsigned int* bf     = (unsigned int*)alloc(256 * 4);       // bucket_fill
    __half*       w1s    = (__half*)alloc(128 * 128 * 2);       // swizzled W1
    __half*       w2s    = (__half*)alloc(128 * 64 * 2);        // swizzled W2
    int*          col    = (int*)alloc((size_t)E * 4);
    __half*       A      = (__half*)alloc((size_t)N * 128 * 2); // T1'/T2' fp16
    __half*       B      = (__half*)alloc((size_t)N * 128 * 2); // h fp16
    unsigned int* ebuf   = (unsigned int*)alloc((size_t)E * 4);

    // 1. CSR build: bucket hist -> scan -> partition -> per-bucket scatter
    hipMemsetAsync(bcount, 0, 256 * 4, stream);
    bucket_hist_kernel<<<(E + 4095) / 4096, 256, 0, stream>>>(dst, E, bcount, NB);
    bucket_scan_kernel<<<1, 256, 0, stream>>>(bcount, bb, bf, NB, E);
    partition_kernel<<<(E + P2_T * P2_I - 1) / (P2_T * P2_I), P2_T, 0, stream>>>(src, dst, bf, ebuf, E, NB);
    bucket_scatter2_kernel<<<NB, 256, 0, stream>>>(ebuf, bb, cursor, deg, dinv, col, N);
    // now cursor[i] == rowend(i); rowstart(i) = cursor[i] - deg[i]; dinv ready

    // 1b. swizzle weights into MFMA fragment order (runs alongside CSR chain)
    swizzle_w_kernel<<<1, 256, 0, stream>>>(W1, W2, w1s, w2s);

    // 2. T1' = dinv * (x @ W1) [MFMA, fp16 out];  h = relu(dinv*(pull) + b1)
    gemm1_mfma_kernel<<<(N + 63) / 64, 256, 0, stream>>>(x, w1s, dinv, A, N);
    pull_agg1_kernel<<<(N + 3) / 4, 256, 0, stream>>>(A, col, cursor, deg, dinv, b1, B, N);

    // 3. T2' = dinv * (h @ W2) [MFMA];  out = logsoftmax(dinv*(pull) + b2)
    gemm2_mfma_kernel<<<(N + 63) / 64, 256, 0, stream>>>(B, w2s, dinv, A, N);
    pull_agg2_kernel<<<(N + 3) / 4, 256, 0, stream>>>(A, col, cursor, deg, dinv, b2, out, N);
}

// Round 6
// 299.442 us; speedup vs baseline: 1.0616x; 1.0616x over previous
//
#include <hip/hip_runtime.h>
#include <hip/hip_fp16.h>

// ---------------------------------------------------------------------------
// GCN 2-layer forward:  out = log_softmax( A_hat * relu(A_hat * (x W1) + b1) W2 + b2 )
// A_hat = D^-1/2 (A + I) D^-1/2, deg on dst. Edge index arrives as int32.
//
// R13: both pull kernels now run MULTIPLE independent gather chains per wave
// (per-wave serial-chain ceiling diagnosed in r12: both pulls pinned at
// 26.4G edges/s regardless of bytes).
//   pull_agg1: 2 nodes/wave, paired 8-bursts (two col->row chains overlap).
//   pull_agg2: each 32-lane half owns one node end-to-end (2 parallel nodes
//   per wave, no cross-half combine). CSR build + MFMA GEMMs unchanged.
// ---------------------------------------------------------------------------

#define BSHIFT 9
#define BSIZE  512            // nodes per bucket; NB = ceil(N/512) = 196 < 256
#define P2_T   1024
#define P2_I   16             // edges staged per thread in partition pass

using half8  = __attribute__((ext_vector_type(8))) _Float16;
using half2v = __attribute__((ext_vector_type(2))) _Float16;
using f32x4  = __attribute__((ext_vector_type(4))) float;

// --- pass 1: per-bucket edge counts (coalesced dst read, LDS histogram) ----
__global__ __launch_bounds__(256) void bucket_hist_kernel(const int* __restrict__ dst, int E,
                                                          unsigned int* __restrict__ bcount, int NB) {
    __shared__ unsigned int h[256];
    int t = threadIdx.x;
    h[t] = 0u;
    __syncthreads();
    for (int i = blockIdx.x * 256 + t; i < E; i += gridDim.x * 256)
        atomicAdd(&h[dst[i] >> BSHIFT], 1u);
    __syncthreads();
    if (t < NB && h[t]) atomicAdd(&bcount[t], h[t]);
}

// --- scan bucket counts -> bucket_base bb[0..NB], bucket_fill bf -----------
__global__ __launch_bounds__(256) void bucket_scan_kernel(const unsigned int* __restrict__ bcount,
                                                          unsigned int* __restrict__ bb,
                                                          unsigned int* __restrict__ bf,
                                                          int NB, int E) {
    __shared__ unsigned int s[256];
    int t = threadIdx.x;
    unsigned int v = (t < NB) ? bcount[t] : 0u;
    s[t] = v;
    __syncthreads();
    for (int off = 1; off < 256; off <<= 1) {
        unsigned int u = s[t];
        if (t >= off) u += s[t - off];
        __syncthreads();
        s[t] = u;
        __syncthreads();
    }
    if (t < NB) {
        unsigned int ex = s[t] - v;
        bb[t] = ex;
        bf[t] = ex;
    }
    if (t == 0) bb[NB] = (unsigned int)E;
}

// --- pass 2: partition edges into dst-buckets, packed src|dstLocal<<17 -----
__global__ __launch_bounds__(1024) void partition_kernel(const int* __restrict__ src,
                                                         const int* __restrict__ dst,
                                                         unsigned int* __restrict__ bucket_fill,
                                                         unsigned int* __restrict__ ebuf,
                                                         int E, int NB) {
    __shared__ unsigned int hist[256];
    __shared__ unsigned int cur[256];
    int t = threadIdx.x;
    if (t < 256) hist[t] = 0u;
    __syncthreads();
    size_t base = (size_t)blockIdx.x * (P2_T * P2_I);
    int sv[P2_I], dv[P2_I];
#pragma unroll
    for (int i = 0; i < P2_I; ++i) {
        size_t idx = base + (size_t)i * P2_T + t;
        if (idx < (size_t)E) {
            sv[i] = src[idx];
            dv[i] = dst[idx];
            atomicAdd(&hist[dv[i] >> BSHIFT], 1u);
        } else dv[i] = -1;
    }
    __syncthreads();
    if (t < NB && hist[t] > 0u) cur[t] = atomicAdd(&bucket_fill[t], hist[t]);
    __syncthreads();
#pragma unroll
    for (int i = 0; i < P2_I; ++i) {
        if (dv[i] >= 0) {
            int b = dv[i] >> BSHIFT;
            unsigned int pos = atomicAdd(&cur[b], 1u);
            ebuf[pos] = (unsigned int)sv[i] | ((unsigned int)(dv[i] & (BSIZE - 1)) << 17);
        }
    }
}

// --- pass 3: per-bucket deg/dinv/rowptr in LDS + scatter; cursor=rowend ----
__global__ __launch_bounds__(256) void bucket_scatter2_kernel(const unsigned int* __restrict__ ebuf,
                                                              const unsigned int* __restrict__ bb,
                                                              unsigned int* __restrict__ cursor,
                                                              unsigned int* __restrict__ deg,
                                                              float* __restrict__ dinv,
                                                              int* __restrict__ col, int N) {
    __shared__ unsigned int ldeg[BSIZE];
    __shared__ unsigned int lcur[BSIZE];
    __shared__ unsigned int part[256];
    int b = blockIdx.x, t = threadIdx.x;
    int node0 = b << BSHIFT;
    int nn = min(BSIZE, N - node0);
    ldeg[t] = 0u;
    ldeg[t + 256] = 0u;
    __syncthreads();
    unsigned int e0 = bb[b], e1 = bb[b + 1];
    for (unsigned int e = e0 + t; e < e1; e += 256)
        atomicAdd(&ldeg[ebuf[e] >> 17], 1u);
    __syncthreads();
    unsigned int a0 = ldeg[2 * t], a1 = ldeg[2 * t + 1];
    part[t] = a0 + a1;
    __syncthreads();
    for (int off = 1; off < 256; off <<= 1) {
        unsigned int u = part[t];
        if (t >= off) u += part[t - off];
        __syncthreads();
        part[t] = u;
        __syncthreads();
    }
    unsigned int ex = part[t] - (a0 + a1);
    lcur[2 * t]     = e0 + ex;
    lcur[2 * t + 1] = e0 + ex + a0;
    __syncthreads();
    for (unsigned int e = e0 + t; e < e1; e += 256) {
        unsigned int p = ebuf[e];
        unsigned int pos = atomicAdd(&lcur[p >> 17], 1u);
        col[pos] = (int)(p & 0x1FFFFu);
    }
    __syncthreads();
    for (int i = t; i < nn; i += 256) {
        unsigned int d = ldeg[i];
        deg[node0 + i] = d;
        dinv[node0 + i] = rsqrtf((float)(d + 1u));
        cursor[node0 + i] = lcur[i];
    }
}

// --- swizzle W1 (128x128) and W2 (128x64) into MFMA B-fragment order -------
// w1s[((c*4+s)*64+l)*8+j] = W[k][n], k=(l>>4)*8+j+32s, n=16c+(l&15)
__global__ __launch_bounds__(256) void swizzle_w_kernel(const float* __restrict__ W1,
                                                        const float* __restrict__ W2,
                                                        __half* __restrict__ w1s,
                                                        __half* __restrict__ w2s) {
    int t = threadIdx.x;
    for (int i = t; i < 8 * 4 * 64 * 8; i += 256) {   // W1: 8 col-tiles
        int j = i & 7, l = (i >> 3) & 63, s = (i >> 9) & 3, c = i >> 11;
        int k = ((l >> 4) * 8) + j + 32 * s;
        int nn = 16 * c + (l & 15);
        w1s[i] = __float2half(W1[k * 128 + nn]);
    }
    for (int i = t; i < 4 * 4 * 64 * 8; i += 256) {   // W2: 4 col-tiles
        int j = i & 7, l = (i >> 3) & 63, s = (i >> 9) & 3, c = i >> 11;
        int k = ((l >> 4) * 8) + j + 32 * s;
        int nn = 16 * c + (l & 15);
        w2s[i] = __float2half(W2[k * 64 + nn]);
    }
}

// --- GEMM1 (MFMA): Y[r,128] = f16( dinv[r] * (X[r,128] @ W1) ), X fp32 -----
__global__ __launch_bounds__(256) void gemm1_mfma_kernel(const float* __restrict__ X,
                                                         const __half* __restrict__ w1s,
                                                         const float* __restrict__ dinv,
                                                         __half* __restrict__ Y, int n) {
    int t = threadIdx.x;
    int wave = t >> 6, lane = t & 63;
    int quad = lane >> 4, m = lane & 15;
    int rowbase = blockIdx.x * 64 + wave * 16;
    int arow = rowbase + m;
    bool aok = arow < n;
    const float* xr = X + (size_t)arow * 128 + quad * 8;

    half8 afrag[4];
#pragma unroll
    for (int s = 0; s < 4; ++s) {
        float4 p0 = make_float4(0.f, 0.f, 0.f, 0.f), p1 = p0;
        if (aok) {
            p0 = *(const float4*)(xr + s * 32);
            p1 = *(const float4*)(xr + s * 32 + 4);
        }
        afrag[s][0] = (_Float16)p0.x; afrag[s][1] = (_Float16)p0.y;
        afrag[s][2] = (_Float16)p0.z; afrag[s][3] = (_Float16)p0.w;
        afrag[s][4] = (_Float16)p1.x; afrag[s][5] = (_Float16)p1.y;
        afrag[s][6] = (_Float16)p1.z; afrag[s][7] = (_Float16)p1.w;
    }

    const half8* bp = (const half8*)w1s;
    f32x4 acc[8];
#pragma unroll
    for (int c = 0; c < 8; ++c) acc[c] = (f32x4){0.f, 0.f, 0.f, 0.f};
#pragma unroll
    for (int c = 0; c < 8; ++c)
#pragma unroll
        for (int s = 0; s < 4; ++s)
            acc[c] = __builtin_amdgcn_mfma_f32_16x16x32_f16(afrag[s], bp[(c * 4 + s) * 64 + lane], acc[c], 0, 0, 0);

#pragma unroll
    for (int i = 0; i < 4; ++i) {
        int row = rowbase + quad * 4 + i;
        if (row < n) {
            float w = dinv[row];
            __half* yr = Y + (size_t)row * 128 + m;
#pragma unroll
            for (int c = 0; c < 8; ++c) yr[c * 16] = __float2half(acc[c][i] * w);
        }
    }
}

// --- GEMM2 (MFMA): Y[r,64] = f16( dinv[r] * (Xh[r,128] @ W2) ), X fp16 -----
__global__ __launch_bounds__(256) void gemm2_mfma_kernel(const __half* __restrict__ X,
                                                         const __half* __restrict__ w2s,
                                                         const float* __restrict__ dinv,
                                                         __half* __restrict__ Y, int n) {
    int t = threadIdx.x;
    int wave = t >> 6, lane = t & 63;
    int quad = lane >> 4, m = lane & 15;
    int rowbase = blockIdx.x * 64 + wave * 16;
    int arow = rowbase + m;
    bool aok = arow < n;
    const __half* xr = X + (size_t)arow * 128 + quad * 8;

    half8 afrag[4];
#pragma unroll
    for (int s = 0; s < 4; ++s) {
        if (aok) afrag[s] = *(const half8*)(xr + s * 32);
        else     afrag[s] = (half8){0, 0, 0, 0, 0, 0, 0, 0};
    }

    const half8* bp = (const half8*)w2s;
    f32x4 acc[4];
#pragma unroll
    for (int c = 0; c < 4; ++c) acc[c] = (f32x4){0.f, 0.f, 0.f, 0.f};
#pragma unroll
    for (int c = 0; c < 4; ++c)
#pragma unroll
        for (int s = 0; s < 4; ++s)
            acc[c] = __builtin_amdgcn_mfma_f32_16x16x32_f16(afrag[s], bp[(c * 4 + s) * 64 + lane], acc[c], 0, 0, 0);

#pragma unroll
    for (int i = 0; i < 4; ++i) {
        int row = rowbase + quad * 4 + i;
        if (row < n) {
            float w = dinv[row];
            __half* yr = Y + (size_t)row * 64 + m;
#pragma unroll
            for (int c = 0; c < 4; ++c) yr[c * 16] = __float2half(acc[c][i] * w);
        }
    }
}

// --- pull layer 1: H[d] = relu(dinv[d]*(T'[d] + sum T'[col]) + b1), F=128 --
// R13: 2 nodes/wave, paired 8-bursts so the two col->row chains overlap.
__global__ __launch_bounds__(256) void pull_agg1_kernel(const __half* __restrict__ T,
                                                        const int* __restrict__ col,
                                                        const unsigned int* __restrict__ cursor,
                                                        const unsigned int* __restrict__ deg,
                                                        const float* __restrict__ dinv,
                                                        const float* __restrict__ b1,
                                                        __half* __restrict__ H, int N) {
    int pair = blockIdx.x * 4 + (threadIdx.x >> 6);
    int nodeA = pair * 2;
    if (nodeA >= N) return;
    int nodeB = nodeA + 1;
    bool hasB = nodeB < N;
    int lane = threadIdx.x & 63;
    const half2v* __restrict__ Tv = (const half2v*)T;   // row = 64 half2

    unsigned int endA = cursor[nodeA];
    unsigned int eA = endA - deg[nodeA];
    endA = __builtin_amdgcn_readfirstlane(endA);
    eA   = __builtin_amdgcn_readfirstlane(eA);
    unsigned int endB = 0u, eB = 0u;
    if (hasB) { endB = cursor[nodeB]; eB = endB - deg[nodeB]; }
    endB = __builtin_amdgcn_readfirstlane(endB);
    eB   = __builtin_amdgcn_readfirstlane(eB);

    half2v selfA = Tv[(unsigned int)nodeA * 64u + lane];
    float a0 = (float)selfA[0], a1 = (float)selfA[1];
    float c0 = 0.f, c1 = 0.f;
    if (hasB) {
        half2v selfB = Tv[(unsigned int)nodeB * 64u + lane];
        c0 = (float)selfB[0]; c1 = (float)selfB[1];
    }

    // paired 8-bursts: two independent gather chains in flight
    while (eA + 8 <= endA && eB + 8 <= endB) {
        unsigned int sA[8], sB[8];
#pragma unroll
        for (int k = 0; k < 8; ++k) sA[k] = (unsigned int)col[eA + k];
#pragma unroll
        for (int k = 0; k < 8; ++k) sB[k] = (unsigned int)col[eB + k];
        half2v vA[8], vB[8];
#pragma unroll
        for (int k = 0; k < 8; ++k) vA[k] = Tv[sA[k] * 64u + lane];
#pragma unroll
        for (int k = 0; k < 8; ++k) vB[k] = Tv[sB[k] * 64u + lane];
        half2v tA0 = (vA[0] + vA[1]) + (vA[2] + vA[3]);
        half2v tA1 = (vA[4] + vA[5]) + (vA[6] + vA[7]);
        half2v tB0 = (vB[0] + vB[1]) + (vB[2] + vB[3]);
        half2v tB1 = (vB[4] + vB[5]) + (vB[6] + vB[7]);
        a0 += (float)tA0[0] + (float)tA1[0];
        a1 += (float)tA0[1] + (float)tA1[1];
        c0 += (float)tB0[0] + (float)tB1[0];
        c1 += (float)tB0[1] + (float)tB1[1];
        eA += 8; eB += 8;
    }
    // drain A
    for (; eA + 8 <= endA; eA += 8) {
        unsigned int s[8];
#pragma unroll
        for (int k = 0; k < 8; ++k) s[k] = (unsigned int)col[eA + k];
        half2v v[8];
#pragma unroll
        for (int k = 0; k < 8; ++k) v[k] = Tv[s[k] * 64u + lane];
        half2v t0 = (v[0] + v[1]) + (v[2] + v[3]);
        half2v t1 = (v[4] + v[5]) + (v[6] + v[7]);
        a0 += (float)t0[0] + (float)t1[0];
        a1 += (float)t0[1] + (float)t1[1];
    }
    for (; eA + 4 <= endA; eA += 4) {
        unsigned int s0 = (unsigned int)col[eA];
        unsigned int s1 = (unsigned int)col[eA + 1];
        unsigned int s2 = (unsigned int)col[eA + 2];
        unsigned int s3 = (unsigned int)col[eA + 3];
        half2v t = (Tv[s0 * 64u + lane] + Tv[s1 * 64u + lane]) +
                   (Tv[s2 * 64u + lane] + Tv[s3 * 64u + lane]);
        a0 += (float)t[0];
        a1 += (float)t[1];
    }
    for (; eA < endA; ++eA) {
        half2v v0 = Tv[(unsigned int)col[eA] * 64u + lane];
        a0 += (float)v0[0];
        a1 += (float)v0[1];
    }
    // drain B
    for (; eB + 8 <= endB; eB += 8) {
        unsigned int s[8];
#pragma unroll
        for (int k = 0; k < 8; ++k) s[k] = (unsigned int)col[eB + k];
        half2v v[8];
#pragma unroll
        for (int k = 0; k < 8; ++k) v[k] = Tv[s[k] * 64u + lane];
        half2v t0 = (v[0] + v[1]) + (v[2] + v[3]);
        half2v t1 = (v[4] + v[5]) + (v[6] + v[7]);
        c0 += (float)t0[0] + (float)t1[0];
        c1 += (float)t0[1] + (float)t1[1];
    }
    for (; eB + 4 <= endB; eB += 4) {
        unsigned int s0 = (unsigned int)col[eB];
        unsigned int s1 = (unsigned int)col[eB + 1];
        unsigned int s2 = (unsigned int)col[eB + 2];
        unsigned int s3 = (unsigned int)col[eB + 3];
        half2v t = (Tv[s0 * 64u + lane] + Tv[s1 * 64u + lane]) +
                   (Tv[s2 * 64u + lane] + Tv[s3 * 64u + lane]);
        c0 += (float)t[0];
        c1 += (float)t[1];
    }
    for (; eB < endB; ++eB) {
        half2v v0 = Tv[(unsigned int)col[eB] * 64u + lane];
        c0 += (float)v0[0];
        c1 += (float)v0[1];
    }

    float2 b = ((const float2*)b1)[lane];
    float wA = dinv[nodeA];
    float hx = fmaxf(fmaf(wA, a0, b.x), 0.f);
    float hy = fmaxf(fmaf(wA, a1, b.y), 0.f);
    ((__half2*)H)[(unsigned int)nodeA * 64u + lane] = __floats2half2_rn(hx, hy);
    if (hasB) {
        float wB = dinv[nodeB];
        float gx = fmaxf(fmaf(wB, c0, b.x), 0.f);
        float gy = fmaxf(fmaf(wB, c1, b.y), 0.f);
        ((__half2*)H)[(unsigned int)nodeB * 64u + lane] = __floats2half2_rn(gx, gy);
    }
}

// --- pull layer 2 + logsoftmax: out[d] = lsm(dinv[d]*sum + b2), F=64 -------
// R13: each 32-lane half owns one node end-to-end (2 parallel nodes/wave).
__global__ __launch_bounds__(256) void pull_agg2_kernel(const __half* __restrict__ T,
                                                        const int* __restrict__ col,
                                                        const unsigned int* __restrict__ cursor,
                                                        const unsigned int* __restrict__ deg,
                                                        const float* __restrict__ dinv,
                                                        const float* __restrict__ b2,
                                                        float* __restrict__ OUT, int N) {
    int node = blockIdx.x * 8 + (threadIdx.x >> 5);     // half-id within block
    if (node >= N) return;
    int c2 = threadIdx.x & 31;                          // col pair
    unsigned int end = cursor[node];
    unsigned int e = end - deg[node];
    const half2v* __restrict__ Tv = (const half2v*)T;   // row = 32 half2

    half2v s = Tv[(unsigned int)node * 32u + c2];       // self loop
    float acc0 = (float)s[0], acc1 = (float)s[1];

    for (; e + 8 <= end; e += 8) {                      // 8 rows in flight
        unsigned int s0 = (unsigned int)col[e];
        unsigned int s1 = (unsigned int)col[e + 1];
        unsigned int s2 = (unsigned int)col[e + 2];
        unsigned int s3 = (unsigned int)col[e + 3];
        unsigned int s4 = (unsigned int)col[e + 4];
        unsigned int s5 = (unsigned int)col[e + 5];
        unsigned int s6 = (unsigned int)col[e + 6];
        unsigned int s7 = (unsigned int)col[e + 7];
        half2v v0 = Tv[s0 * 32u + c2];
        half2v v1 = Tv[s1 * 32u + c2];
        half2v v2 = Tv[s2 * 32u + c2];
        half2v v3 = Tv[s3 * 32u + c2];
        half2v v4 = Tv[s4 * 32u + c2];
        half2v v5 = Tv[s5 * 32u + c2];
        half2v v6 = Tv[s6 * 32u + c2];
        half2v v7 = Tv[s7 * 32u + c2];
        half2v t0 = (v0 + v1) + (v2 + v3);
        half2v t1 = (v4 + v5) + (v6 + v7);
        acc0 += (float)t0[0] + (float)t1[0];
        acc1 += (float)t0[1] + (float)t1[1];
    }
    for (; e + 4 <= end; e += 4) {
        unsigned int s0 = (unsigned int)col[e];
        unsigned int s1 = (unsigned int)col[e + 1];
        unsigned int s2 = (unsigned int)col[e + 2];
        unsigned int s3 = (unsigned int)col[e + 3];
        half2v t = (Tv[s0 * 32u + c2] + Tv[s1 * 32u + c2]) +
                   (Tv[s2 * 32u + c2] + Tv[s3 * 32u + c2]);
        acc0 += (float)t[0];
        acc1 += (float)t[1];
    }
    for (; e < end; ++e) {
        half2v v0 = Tv[(unsigned int)col[e] * 32u + c2];
        acc0 += (float)v0[0];
        acc1 += (float)v0[1];
    }

    float w = dinv[node];
    float2 b = ((const float2*)b2)[c2];
    float vx = fmaf(w, acc0, b.x);
    float vy = fmaf(w, acc1, b.y);
    float m = fmaxf(vx, vy);
#pragma unroll
    for (int off = 16; off > 0; off >>= 1) m = fmaxf(m, __shfl_xor(m, off));
    float sum = __expf(vx - m) + __expf(vy - m);
#pragma unroll
    for (int off = 16; off > 0; off >>= 1) sum += __shfl_xor(sum, off);
    float ls = m + logf(sum);
    float2 o;
    o.x = vx - ls;
    o.y = vy - ls;
    ((float2*)OUT)[(unsigned int)node * 32u + c2] = o;
}

extern "C" void kernel_launch(void* const* d_in, const int* in_sizes, int n_in,
                              void* d_out, int out_size, void* d_ws, size_t ws_size,
                              hipStream_t stream) {
    const float* x   = (const float*)d_in[0];
    const int*   ei  = (const int*)d_in[1];   // int32 per harness contract
    const float* W1  = (const float*)d_in[2];
    const float* b1  = (const float*)d_in[3];
    const float* W2  = (const float*)d_in[4];
    const float* b2  = (const float*)d_in[5];
    float*       out = (float*)d_out;

    const int N = in_sizes[0] / 128;      // 100000
    const int E = in_sizes[1] / 2;        // 1600000
    const int* src = ei;
    const int* dst = ei + E;
    const int NB = (N + BSIZE - 1) >> BSHIFT;   // dst buckets (196 <= 256)

    // workspace layout
    char* ws = (char*)d_ws;
    size_t off = 0;
    auto alloc = [&](size_t bytes) { void* p = ws + off; off = (off + bytes + 255) & ~(size_t)255; return p; };
    unsigned int* deg    = (unsigned int*)alloc((size_t)N * 4);
    float*        dinv   = (float*)alloc((size_t)N * 4);
    unsigned int* cursor = (unsigned int*)alloc((size_t)N * 4);
    unsigned int* bcount = (unsigned int*)alloc(256 * 4);
    unsigned int* bb     = (unsigned int*)alloc(257 * 4);       // bucket_base
    unsigned int* bf     = (unsigned int*)alloc(256 * 4);       // bucket_fill
    __half*       w1s    = (__half*)alloc(128 * 128 * 2);       // swizzled W1
    __half*       w2s    = (__half*)alloc(128 * 64 * 2);        // swizzled W2
    int*          col    = (int*)alloc((size_t)E * 4);
    __half*       A      = (__half*)alloc((size_t)N * 128 * 2); // T1'/T2' fp16
    __half*       B      = (__half*)alloc((size_t)N * 128 * 2); // h fp16
    unsigned int* ebuf   = (unsigned int*)alloc((size_t)E * 4);

    // 1. CSR build: bucket hist -> scan -> partition -> per-bucket scatter
    hipMemsetAsync(bcount, 0, 256 * 4, stream);
    bucket_hist_kernel<<<(E + 4095) / 4096, 256, 0, stream>>>(dst, E, bcount, NB);
    bucket_scan_kernel<<<1, 256, 0, stream>>>(bcount, bb, bf, NB, E);
    partition_kernel<<<(E + P2_T * P2_I - 1) / (P2_T * P2_I), P2_T, 0, stream>>>(src, dst, bf, ebuf, E, NB);
    bucket_scatter2_kernel<<<NB, 256, 0, stream>>>(ebuf, bb, cursor, deg, dinv, col, N);
    // now cursor[i] == rowend(i); rowstart(i) = cursor[i] - deg[i]; dinv ready

    // 1b. swizzle weights into MFMA fragment order (runs alongside CSR chain)
    swizzle_w_kernel<<<1, 256, 0, stream>>>(W1, W2, w1s, w2s);

    // 2. T1' = dinv * (x @ W1) [MFMA, fp16 out];  h = relu(dinv*(pull) + b1)
    gemm1_mfma_kernel<<<(N + 63) / 64, 256, 0, stream>>>(x, w1s, dinv, A, N);
    pull_agg1_kernel<<<(N + 7) / 8, 256, 0, stream>>>(A, col, cursor, deg, dinv, b1, B, N);

    // 3. T2' = dinv * (h @ W2) [MFMA];  out = logsoftmax(dinv*(pull) + b2)
    gemm2_mfma_kernel<<<(N + 63) / 64, 256, 0, stream>>>(B, w2s, dinv, A, N);
    pull_agg2_kernel<<<(N + 7) / 8, 256, 0, stream>>>(A, col, cursor, deg, dinv, b2, out, N);
}

// Round 7
// 282.580 us; speedup vs baseline: 1.1249x; 1.0597x over previous
//
#include <hip/hip_runtime.h>
#include <hip/hip_fp16.h>

// ---------------------------------------------------------------------------
// GCN 2-layer forward:  out = log_softmax( A_hat * relu(A_hat * (x W1) + b1) W2 + b2 )
// A_hat = D^-1/2 (A + I) D^-1/2, deg on dst. Edge index arrives as int32.
//
// R14: gathered tensors quantized to fp8 e4m3 (OCP). Diagnosis: agg1 pinned
// at 61us across 4 schedules -> random-line rate ceiling (4 lines/edge).
// T1' fp8: 128B rows (2 lines/edge, 12.8MB table). T2' fp8: 64B rows
// (1 line/edge, 6.4MB ~L2-resident). GEMMs stay fp16 MFMA, H stays fp16;
// accumulation fp32. Also: swizzle_w widened 1 -> 64 blocks (was a
// single-block latency-bound kernel on the serial path).
// ---------------------------------------------------------------------------

#define BSHIFT 9
#define BSIZE  512            // nodes per bucket; NB = ceil(N/512) = 196 < 256
#define P2_T   1024
#define P2_I   16             // edges staged per thread in partition pass

using half8  = __attribute__((ext_vector_type(8))) _Float16;
using half2v = __attribute__((ext_vector_type(2))) _Float16;
using f32x4  = __attribute__((ext_vector_type(4))) float;

__device__ __forceinline__ unsigned char f32_to_fp8(float v) {
    int p = __builtin_amdgcn_cvt_pk_fp8_f32(v, v, 0, false);
    return (unsigned char)(p & 0xff);
}

// --- pass 1: per-bucket edge counts (coalesced dst read, LDS histogram) ----
__global__ __launch_bounds__(256) void bucket_hist_kernel(const int* __restrict__ dst, int E,
                                                          unsigned int* __restrict__ bcount, int NB) {
    __shared__ unsigned int h[256];
    int t = threadIdx.x;
    h[t] = 0u;
    __syncthreads();
    for (int i = blockIdx.x * 256 + t; i < E; i += gridDim.x * 256)
        atomicAdd(&h[dst[i] >> BSHIFT], 1u);
    __syncthreads();
    if (t < NB && h[t]) atomicAdd(&bcount[t], h[t]);
}

// --- scan bucket counts -> bucket_base bb[0..NB], bucket_fill bf -----------
__global__ __launch_bounds__(256) void bucket_scan_kernel(const unsigned int* __restrict__ bcount,
                                                          unsigned int* __restrict__ bb,
                                                          unsigned int* __restrict__ bf,
                                                          int NB, int E) {
    __shared__ unsigned int s[256];
    int t = threadIdx.x;
    unsigned int v = (t < NB) ? bcount[t] : 0u;
    s[t] = v;
    __syncthreads();
    for (int off = 1; off < 256; off <<= 1) {
        unsigned int u = s[t];
        if (t >= off) u += s[t - off];
        __syncthreads();
        s[t] = u;
        __syncthreads();
    }
    if (t < NB) {
        unsigned int ex = s[t] - v;
        bb[t] = ex;
        bf[t] = ex;
    }
    if (t == 0) bb[NB] = (unsigned int)E;
}

// --- pass 2: partition edges into dst-buckets, packed src|dstLocal<<17 -----
__global__ __launch_bounds__(1024) void partition_kernel(const int* __restrict__ src,
                                                         const int* __restrict__ dst,
                                                         unsigned int* __restrict__ bucket_fill,
                                                         unsigned int* __restrict__ ebuf,
                                                         int E, int NB) {
    __shared__ unsigned int hist[256];
    __shared__ unsigned int cur[256];
    int t = threadIdx.x;
    if (t < 256) hist[t] = 0u;
    __syncthreads();
    size_t base = (size_t)blockIdx.x * (P2_T * P2_I);
    int sv[P2_I], dv[P2_I];
#pragma unroll
    for (int i = 0; i < P2_I; ++i) {
        size_t idx = base + (size_t)i * P2_T + t;
        if (idx < (size_t)E) {
            sv[i] = src[idx];
            dv[i] = dst[idx];
            atomicAdd(&hist[dv[i] >> BSHIFT], 1u);
        } else dv[i] = -1;
    }
    __syncthreads();
    if (t < NB && hist[t] > 0u) cur[t] = atomicAdd(&bucket_fill[t], hist[t]);
    __syncthreads();
#pragma unroll
    for (int i = 0; i < P2_I; ++i) {
        if (dv[i] >= 0) {
            int b = dv[i] >> BSHIFT;
            unsigned int pos = atomicAdd(&cur[b], 1u);
            ebuf[pos] = (unsigned int)sv[i] | ((unsigned int)(dv[i] & (BSIZE - 1)) << 17);
        }
    }
}

// --- pass 3: per-bucket deg/dinv/rowptr in LDS + scatter; cursor=rowend ----
__global__ __launch_bounds__(256) void bucket_scatter2_kernel(const unsigned int* __restrict__ ebuf,
                                                              const unsigned int* __restrict__ bb,
                                                              unsigned int* __restrict__ cursor,
                                                              unsigned int* __restrict__ deg,
                                                              float* __restrict__ dinv,
                                                              int* __restrict__ col, int N) {
    __shared__ unsigned int ldeg[BSIZE];
    __shared__ unsigned int lcur[BSIZE];
    __shared__ unsigned int part[256];
    int b = blockIdx.x, t = threadIdx.x;
    int node0 = b << BSHIFT;
    int nn = min(BSIZE, N - node0);
    ldeg[t] = 0u;
    ldeg[t + 256] = 0u;
    __syncthreads();
    unsigned int e0 = bb[b], e1 = bb[b + 1];
    for (unsigned int e = e0 + t; e < e1; e += 256)
        atomicAdd(&ldeg[ebuf[e] >> 17], 1u);
    __syncthreads();
    unsigned int a0 = ldeg[2 * t], a1 = ldeg[2 * t + 1];
    part[t] = a0 + a1;
    __syncthreads();
    for (int off = 1; off < 256; off <<= 1) {
        unsigned int u = part[t];
        if (t >= off) u += part[t - off];
        __syncthreads();
        part[t] = u;
        __syncthreads();
    }
    unsigned int ex = part[t] - (a0 + a1);
    lcur[2 * t]     = e0 + ex;
    lcur[2 * t + 1] = e0 + ex + a0;
    __syncthreads();
    for (unsigned int e = e0 + t; e < e1; e += 256) {
        unsigned int p = ebuf[e];
        unsigned int pos = atomicAdd(&lcur[p >> 17], 1u);
        col[pos] = (int)(p & 0x1FFFFu);
    }
    __syncthreads();
    for (int i = t; i < nn; i += 256) {
        unsigned int d = ldeg[i];
        deg[node0 + i] = d;
        dinv[node0 + i] = rsqrtf((float)(d + 1u));
        cursor[node0 + i] = lcur[i];
    }
}

// --- swizzle W1 (128x128) and W2 (128x64) into MFMA B-fragment order -------
// w1s[((c*4+s)*64+l)*8+j] = W[k][n], k=(l>>4)*8+j+32s, n=16c+(l&15)
// R14: multi-block (was 1 block latency-bound on the serial path).
__global__ __launch_bounds__(256) void swizzle_w_kernel(const float* __restrict__ W1,
                                                        const float* __restrict__ W2,
                                                        __half* __restrict__ w1s,
                                                        __half* __restrict__ w2s) {
    int t = blockIdx.x * 256 + threadIdx.x;
    int stride = gridDim.x * 256;
    for (int i = t; i < 8 * 4 * 64 * 8; i += stride) {   // W1: 8 col-tiles
        int j = i & 7, l = (i >> 3) & 63, s = (i >> 9) & 3, c = i >> 11;
        int k = ((l >> 4) * 8) + j + 32 * s;
        int nn = 16 * c + (l & 15);
        w1s[i] = __float2half(W1[k * 128 + nn]);
    }
    for (int i = t; i < 4 * 4 * 64 * 8; i += stride) {   // W2: 4 col-tiles
        int j = i & 7, l = (i >> 3) & 63, s = (i >> 9) & 3, c = i >> 11;
        int k = ((l >> 4) * 8) + j + 32 * s;
        int nn = 16 * c + (l & 15);
        w2s[i] = __float2half(W2[k * 64 + nn]);
    }
}

// --- GEMM1 (MFMA): Y8[r,128] = fp8( dinv[r] * (X[r,128] @ W1) ), X fp32 ----
__global__ __launch_bounds__(256) void gemm1_mfma_kernel(const float* __restrict__ X,
                                                         const __half* __restrict__ w1s,
                                                         const float* __restrict__ dinv,
                                                         unsigned char* __restrict__ Y8, int n) {
    int t = threadIdx.x;
    int wave = t >> 6, lane = t & 63;
    int quad = lane >> 4, m = lane & 15;
    int rowbase = blockIdx.x * 64 + wave * 16;
    int arow = rowbase + m;
    bool aok = arow < n;
    const float* xr = X + (size_t)arow * 128 + quad * 8;

    half8 afrag[4];
#pragma unroll
    for (int s = 0; s < 4; ++s) {
        float4 p0 = make_float4(0.f, 0.f, 0.f, 0.f), p1 = p0;
        if (aok) {
            p0 = *(const float4*)(xr + s * 32);
            p1 = *(const float4*)(xr + s * 32 + 4);
        }
        afrag[s][0] = (_Float16)p0.x; afrag[s][1] = (_Float16)p0.y;
        afrag[s][2] = (_Float16)p0.z; afrag[s][3] = (_Float16)p0.w;
        afrag[s][4] = (_Float16)p1.x; afrag[s][5] = (_Float16)p1.y;
        afrag[s][6] = (_Float16)p1.z; afrag[s][7] = (_Float16)p1.w;
    }

    const half8* bp = (const half8*)w1s;
    f32x4 acc[8];
#pragma unroll
    for (int c = 0; c < 8; ++c) acc[c] = (f32x4){0.f, 0.f, 0.f, 0.f};
#pragma unroll
    for (int c = 0; c < 8; ++c)
#pragma unroll
        for (int s = 0; s < 4; ++s)
            acc[c] = __builtin_amdgcn_mfma_f32_16x16x32_f16(afrag[s], bp[(c * 4 + s) * 64 + lane], acc[c], 0, 0, 0);

#pragma unroll
    for (int i = 0; i < 4; ++i) {
        int row = rowbase + quad * 4 + i;
        if (row < n) {
            float w = dinv[row];
            unsigned char* yr = Y8 + (size_t)row * 128 + m;
#pragma unroll
            for (int c = 0; c < 8; ++c) yr[c * 16] = f32_to_fp8(acc[c][i] * w);
        }
    }
}

// --- GEMM2 (MFMA): Y8[r,64] = fp8( dinv[r] * (Xh[r,128] @ W2) ), X fp16 ----
__global__ __launch_bounds__(256) void gemm2_mfma_kernel(const __half* __restrict__ X,
                                                         const __half* __restrict__ w2s,
                                                         const float* __restrict__ dinv,
                                                         unsigned char* __restrict__ Y8, int n) {
    int t = threadIdx.x;
    int wave = t >> 6, lane = t & 63;
    int quad = lane >> 4, m = lane & 15;
    int rowbase = blockIdx.x * 64 + wave * 16;
    int arow = rowbase + m;
    bool aok = arow < n;
    const __half* xr = X + (size_t)arow * 128 + quad * 8;

    half8 afrag[4];
#pragma unroll
    for (int s = 0; s < 4; ++s) {
        if (aok) afrag[s] = *(const half8*)(xr + s * 32);
        else     afrag[s] = (half8){0, 0, 0, 0, 0, 0, 0, 0};
    }

    const half8* bp = (const half8*)w2s;
    f32x4 acc[4];
#pragma unroll
    for (int c = 0; c < 4; ++c) acc[c] = (f32x4){0.f, 0.f, 0.f, 0.f};
#pragma unroll
    for (int c = 0; c < 4; ++c)
#pragma unroll
        for (int s = 0; s < 4; ++s)
            acc[c] = __builtin_amdgcn_mfma_f32_16x16x32_f16(afrag[s], bp[(c * 4 + s) * 64 + lane], acc[c], 0, 0, 0);

#pragma unroll
    for (int i = 0; i < 4; ++i) {
        int row = rowbase + quad * 4 + i;
        if (row < n) {
            float w = dinv[row];
            unsigned char* yr = Y8 + (size_t)row * 64 + m;
#pragma unroll
            for (int c = 0; c < 4; ++c) yr[c * 16] = f32_to_fp8(acc[c][i] * w);
        }
    }
}

// --- pull layer 1: H[d] = relu(dinv[d]*(T'[d] + sum T'[col]) + b1), F=128 --
// R14: T' is fp8 (128B rows, 2 lines/edge). 2 nodes/wave, paired 8-bursts.
// Lane l reads features (2l, 2l+1) as ushort -> cvt_pk_f32_fp8 -> fp32 acc.
__global__ __launch_bounds__(256) void pull_agg1_kernel(const unsigned char* __restrict__ T8,
                                                        const int* __restrict__ col,
                                                        const unsigned int* __restrict__ cursor,
                                                        const unsigned int* __restrict__ deg,
                                                        const float* __restrict__ dinv,
                                                        const float* __restrict__ b1,
                                                        __half* __restrict__ H, int N) {
    int pair = blockIdx.x * 4 + (threadIdx.x >> 6);
    int nodeA = pair * 2;
    if (nodeA >= N) return;
    int nodeB = nodeA + 1;
    bool hasB = nodeB < N;
    int lane = threadIdx.x & 63;
    unsigned int boff = (unsigned int)lane << 1;

    unsigned int endA = cursor[nodeA];
    unsigned int eA = endA - deg[nodeA];
    endA = __builtin_amdgcn_readfirstlane(endA);
    eA   = __builtin_amdgcn_readfirstlane(eA);
    unsigned int endB = 0u, eB = 0u;
    if (hasB) { endB = cursor[nodeB]; eB = endB - deg[nodeB]; }
    endB = __builtin_amdgcn_readfirstlane(endB);
    eB   = __builtin_amdgcn_readfirstlane(eB);

    unsigned short uSA = *(const unsigned short*)(T8 + (unsigned int)nodeA * 128u + boff);
    auto fSA = __builtin_amdgcn_cvt_pk_f32_fp8((int)uSA, false);
    float a0 = fSA[0], a1 = fSA[1];
    float c0 = 0.f, c1 = 0.f;
    if (hasB) {
        unsigned short uSB = *(const unsigned short*)(T8 + (unsigned int)nodeB * 128u + boff);
        auto fSB = __builtin_amdgcn_cvt_pk_f32_fp8((int)uSB, false);
        c0 = fSB[0]; c1 = fSB[1];
    }

    // paired 8-bursts: two independent gather chains in flight
    while (eA + 8 <= endA && eB + 8 <= endB) {
        unsigned int sA[8], sB[8];
#pragma unroll
        for (int k = 0; k < 8; ++k) sA[k] = (unsigned int)col[eA + k];
#pragma unroll
        for (int k = 0; k < 8; ++k) sB[k] = (unsigned int)col[eB + k];
        unsigned short vA[8], vB[8];
#pragma unroll
        for (int k = 0; k < 8; ++k) vA[k] = *(const unsigned short*)(T8 + sA[k] * 128u + boff);
#pragma unroll
        for (int k = 0; k < 8; ++k) vB[k] = *(const unsigned short*)(T8 + sB[k] * 128u + boff);
#pragma unroll
        for (int k = 0; k < 8; ++k) {
            auto f = __builtin_amdgcn_cvt_pk_f32_fp8((int)vA[k], false);
            a0 += f[0]; a1 += f[1];
        }
#pragma unroll
        for (int k = 0; k < 8; ++k) {
            auto f = __builtin_amdgcn_cvt_pk_f32_fp8((int)vB[k], false);
            c0 += f[0]; c1 += f[1];
        }
        eA += 8; eB += 8;
    }
    // drain A
    for (; eA + 8 <= endA; eA += 8) {
        unsigned int s[8];
#pragma unroll
        for (int k = 0; k < 8; ++k) s[k] = (unsigned int)col[eA + k];
        unsigned short v[8];
#pragma unroll
        for (int k = 0; k < 8; ++k) v[k] = *(const unsigned short*)(T8 + s[k] * 128u + boff);
#pragma unroll
        for (int k = 0; k < 8; ++k) {
            auto f = __builtin_amdgcn_cvt_pk_f32_fp8((int)v[k], false);
            a0 += f[0]; a1 += f[1];
        }
    }
    for (; eA < endA; ++eA) {
        unsigned short u = *(const unsigned short*)(T8 + (unsigned int)col[eA] * 128u + boff);
        auto f = __builtin_amdgcn_cvt_pk_f32_fp8((int)u, false);
        a0 += f[0]; a1 += f[1];
    }
    // drain B
    for (; eB + 8 <= endB; eB += 8) {
        unsigned int s[8];
#pragma unroll
        for (int k = 0; k < 8; ++k) s[k] = (unsigned int)col[eB + k];
        unsigned short v[8];
#pragma unroll
        for (int k = 0; k < 8; ++k) v[k] = *(const unsigned short*)(T8 + s[k] * 128u + boff);
#pragma unroll
        for (int k = 0; k < 8; ++k) {
            auto f = __builtin_amdgcn_cvt_pk_f32_fp8((int)v[k], false);
            c0 += f[0]; c1 += f[1];
        }
    }
    for (; eB < endB; ++eB) {
        unsigned short u = *(const unsigned short*)(T8 + (unsigned int)col[eB] * 128u + boff);
        auto f = __builtin_amdgcn_cvt_pk_f32_fp8((int)u, false);
        c0 += f[0]; c1 += f[1];
    }

    float2 b = ((const float2*)b1)[lane];
    float wA = dinv[nodeA];
    float hx = fmaxf(fmaf(wA, a0, b.x), 0.f);
    float hy = fmaxf(fmaf(wA, a1, b.y), 0.f);
    ((__half2*)H)[(unsigned int)nodeA * 64u + lane] = __floats2half2_rn(hx, hy);
    if (hasB) {
        float wB = dinv[nodeB];
        float gx = fmaxf(fmaf(wB, c0, b.x), 0.f);
        float gy = fmaxf(fmaf(wB, c1, b.y), 0.f);
        ((__half2*)H)[(unsigned int)nodeB * 64u + lane] = __floats2half2_rn(gx, gy);
    }
}

// --- pull layer 2 + logsoftmax: out[d] = lsm(dinv[d]*sum + b2), F=64 -------
// R14: T2' fp8 (64B rows, ONE line per edge). Each 32-lane half owns a node.
__global__ __launch_bounds__(256) void pull_agg2_kernel(const unsigned char* __restrict__ T8,
                                                        const int* __restrict__ col,
                                                        const unsigned int* __restrict__ cursor,
                                                        const unsigned int* __restrict__ deg,
                                                        const float* __restrict__ dinv,
                                                        const float* __restrict__ b2,
                                                        float* __restrict__ OUT, int N) {
    int node = blockIdx.x * 8 + (threadIdx.x >> 5);     // half-id within block
    if (node >= N) return;
    int c2 = threadIdx.x & 31;                          // col pair
    unsigned int boff = (unsigned int)c2 << 1;
    unsigned int end = cursor[node];
    unsigned int e = end - deg[node];

    unsigned short uS = *(const unsigned short*)(T8 + (unsigned int)node * 64u + boff);
    auto fS = __builtin_amdgcn_cvt_pk_f32_fp8((int)uS, false);
    float acc0 = fS[0], acc1 = fS[1];

    for (; e + 8 <= end; e += 8) {                      // 8 rows in flight
        unsigned int s[8];
#pragma unroll
        for (int k = 0; k < 8; ++k) s[k] = (unsigned int)col[e + k];
        unsigned short v[8];
#pragma unroll
        for (int k = 0; k < 8; ++k) v[k] = *(const unsigned short*)(T8 + s[k] * 64u + boff);
#pragma unroll
        for (int k = 0; k < 8; ++k) {
            auto f = __builtin_amdgcn_cvt_pk_f32_fp8((int)v[k], false);
            acc0 += f[0]; acc1 += f[1];
        }
    }
    for (; e < end; ++e) {
        unsigned short u = *(const unsigned short*)(T8 + (unsigned int)col[e] * 64u + boff);
        auto f = __builtin_amdgcn_cvt_pk_f32_fp8((int)u, false);
        acc0 += f[0]; acc1 += f[1];
    }

    float w = dinv[node];
    float2 b = ((const float2*)b2)[c2];
    float vx = fmaf(w, acc0, b.x);
    float vy = fmaf(w, acc1, b.y);
    float m = fmaxf(vx, vy);
#pragma unroll
    for (int off = 16; off > 0; off >>= 1) m = fmaxf(m, __shfl_xor(m, off));
    float sum = __expf(vx - m) + __expf(vy - m);
#pragma unroll
    for (int off = 16; off > 0; off >>= 1) sum += __shfl_xor(sum, off);
    float ls = m + logf(sum);
    float2 o;
    o.x = vx - ls;
    o.y = vy - ls;
    ((float2*)OUT)[(unsigned int)node * 32u + c2] = o;
}

extern "C" void kernel_launch(void* const* d_in, const int* in_sizes, int n_in,
                              void* d_out, int out_size, void* d_ws, size_t ws_size,
                              hipStream_t stream) {
    const float* x   = (const float*)d_in[0];
    const int*   ei  = (const int*)d_in[1];   // int32 per harness contract
    const float* W1  = (const float*)d_in[2];
    const float* b1  = (const float*)d_in[3];
    const float* W2  = (const float*)d_in[4];
    const float* b2  = (const float*)d_in[5];
    float*       out = (float*)d_out;

    const int N = in_sizes[0] / 128;      // 100000
    const int E = in_sizes[1] / 2;        // 1600000
    const int* src = ei;
    const int* dst = ei + E;
    const int NB = (N + BSIZE - 1) >> BSHIFT;   // dst buckets (196 <= 256)

    // workspace layout
    char* ws = (char*)d_ws;
    size_t off = 0;
    auto alloc = [&](size_t bytes) { void* p = ws + off; off = (off + bytes + 255) & ~(size_t)255; return p; };
    unsigned int* deg    = (unsigned int*)alloc((size_t)N * 4);
    float*        dinv   = (float*)alloc((size_t)N * 4);
    unsigned int* cursor = (unsigned int*)alloc((size_t)N * 4);
    unsigned int* bcount = (unsigned int*)alloc(256 * 4);
    unsigned int* bb     = (unsigned int*)alloc(257 * 4);       // bucket_base
    unsigned int* bf     = (unsigned int*)alloc(256 * 4);       // bucket_fill
    __half*       w1s    = (__half*)alloc(128 * 128 * 2);       // swizzled W1
    __half*       w2s    = (__half*)alloc(128 * 64 * 2);        // swizzled W2
    int*          col    = (int*)alloc((size_t)E * 4);
    unsigned char* A     = (unsigned char*)alloc((size_t)N * 128); // T1'/T2' fp8
    __half*       B      = (__half*)alloc((size_t)N * 128 * 2);    // h fp16
    unsigned int* ebuf   = (unsigned int*)alloc((size_t)E * 4);

    // 1. CSR build: bucket hist -> scan -> partition -> per-bucket scatter
    hipMemsetAsync(bcount, 0, 256 * 4, stream);
    bucket_hist_kernel<<<(E + 4095) / 4096, 256, 0, stream>>>(dst, E, bcount, NB);
    bucket_scan_kernel<<<1, 256, 0, stream>>>(bcount, bb, bf, NB, E);
    partition_kernel<<<(E + P2_T * P2_I - 1) / (P2_T * P2_I), P2_T, 0, stream>>>(src, dst, bf, ebuf, E, NB);
    bucket_scatter2_kernel<<<NB, 256, 0, stream>>>(ebuf, bb, cursor, deg, dinv, col, N);
    // now cursor[i] == rowend(i); rowstart(i) = cursor[i] - deg[i]; dinv ready

    // 1b. swizzle weights into MFMA fragment order (64 blocks; was 1)
    swizzle_w_kernel<<<64, 256, 0, stream>>>(W1, W2, w1s, w2s);

    // 2. T1' = fp8(dinv * (x @ W1)) [MFMA];  h = relu(dinv*(pull) + b1)
    gemm1_mfma_kernel<<<(N + 63) / 64, 256, 0, stream>>>(x, w1s, dinv, A, N);
    pull_agg1_kernel<<<(N + 7) / 8, 256, 0, stream>>>(A, col, cursor, deg, dinv, b1, B, N);

    // 3. T2' = fp8(dinv * (h @ W2)) [MFMA];  out = logsoftmax(dinv*(pull) + b2)
    gemm2_mfma_kernel<<<(N + 63) / 64, 256, 0, stream>>>(B, w2s, dinv, A, N);
    pull_agg2_kernel<<<(N + 7) / 8, 256, 0, stream>>>(A, col, cursor, deg, dinv, b2, out, N);
}